// Round 1
// 390.534 us; speedup vs baseline: 1.1437x; 1.1437x over previous
//
#include <hip/hip_runtime.h>
#include <stdint.h>

#define NTOK 98
#define CDIM 96
#define LDK 104   // k row stride (elems); 98 rows stored, nt=6 reads rows 98..111
                  // overflow into vT (finite bf16, masked in softmax) by design
#define LDV 120   // vT col count: tokens 0..111 real/junk, 112..119 zeroed,
                  // reads of 120..127 spill into next row / zeroed tail pad

typedef __bf16 bf16x8 __attribute__((ext_vector_type(8)));
typedef __bf16 bf16x2 __attribute__((ext_vector_type(2)));
typedef float f32x4 __attribute__((ext_vector_type(4)));

__device__ __forceinline__ uint16_t f2bfbits(float f) {  // precompute only
  uint32_t u = __builtin_bit_cast(uint32_t, f);
  u += 0x7FFFu + ((u >> 16) & 1u);  // RTNE
  return (uint16_t)(u >> 16);
}

// native v_cvt_pk_bf16_f32 path (RTNE) — compiler emits the packed cvt
__device__ __forceinline__ uint32_t pk2(float a, float b) {
  bf16x2 t;
  t[0] = (__bf16)a;
  t[1] = (__bf16)b;
  return __builtin_bit_cast(uint32_t, t);
}

__device__ __forceinline__ bf16x8 cvt8(const float* p) {
  float4 a = *(const float4*)p;
  float4 b = *(const float4*)(p + 4);
  bf16x8 r;
  r[0] = (__bf16)a.x; r[1] = (__bf16)a.y; r[2] = (__bf16)a.z; r[3] = (__bf16)a.w;
  r[4] = (__bf16)b.x; r[5] = (__bf16)b.y; r[6] = (__bf16)b.z; r[7] = (__bf16)b.w;
  return r;
}

// quad-rechunk: D-layout 4-chunks -> A/B-fragment 8-chunks.
// Source regs hold, per lane (quad_s,l16): packed pairs
//   e0=[off 4q_s+0,1] e1=[off 4q_s+2,3] (parity e: offs 0..15, from tile 2t)
//   o0,o1 likewise for parity o (offs 16..31, tile 2t+1).
// Target lane (quad,l16) fragment wants offs 8*quad+j, j=0..7:
//   j=0..3 <- quad_s=(2*quad)&3, j=4..7 <- quad_s=(2*quad+1)&3,
//   parity e for quad<2, o for quad>=2.  (verified per-element)
__device__ __forceinline__ bf16x8 rechunk(uint32_t e0, uint32_t e1, uint32_t o0,
                                          uint32_t o1, int selA, int selB,
                                          bool lowq) {
  int a0 = __builtin_amdgcn_ds_bpermute(selA, (int)e0);
  int a1 = __builtin_amdgcn_ds_bpermute(selA, (int)e1);
  int b0 = __builtin_amdgcn_ds_bpermute(selB, (int)e0);
  int b1 = __builtin_amdgcn_ds_bpermute(selB, (int)e1);
  int a0o = __builtin_amdgcn_ds_bpermute(selA, (int)o0);
  int a1o = __builtin_amdgcn_ds_bpermute(selA, (int)o1);
  int b0o = __builtin_amdgcn_ds_bpermute(selB, (int)o0);
  int b1o = __builtin_amdgcn_ds_bpermute(selB, (int)o1);
  uint4 w;
  w.x = (uint32_t)(lowq ? a0 : a0o);
  w.y = (uint32_t)(lowq ? a1 : a1o);
  w.z = (uint32_t)(lowq ? b0 : b0o);
  w.w = (uint32_t)(lowq ? b1 : b1o);
  return __builtin_bit_cast(bf16x8, w);
}

// ---------------- precompute: weights -> bf16 fragment order; bias -> dense f32
__global__ void precompute(const float* __restrict__ qkv_w,
                           const float* __restrict__ proj_w,
                           const float* __restrict__ bias_table,
                           const int* __restrict__ rel_index,
                           uint16_t* __restrict__ qkv_wp,
                           uint16_t* __restrict__ proj_wp,
                           float* __restrict__ bias_full) {
  int t = blockIdx.x * blockDim.x + threadIdx.x;
  int stride = gridDim.x * blockDim.x;
  for (int f = t; f < 18 * 3 * 4 * 16 * 8; f += stride) {
    int j = f & 7, l16 = (f >> 3) & 15, quad = (f >> 7) & 3, ktnt = f >> 9;
    int kt = ktnt % 3, nt = ktnt / 3;
    qkv_wp[f] = f2bfbits(qkv_w[(nt * 16 + l16) * CDIM + kt * 32 + quad * 8 + j]);
  }
  for (int f = t; f < 6 * 3 * 4 * 16 * 8; f += stride) {
    int j = f & 7, l16 = (f >> 3) & 15, quad = (f >> 7) & 3, ktnt = f >> 9;
    int kt = ktnt % 3, nt = ktnt / 3;
    proj_wp[f] = f2bfbits(proj_w[(nt * 16 + l16) * CDIM + kt * 32 + quad * 8 + j]);
  }
  for (int f = t; f < 3 * 128 * 112; f += stride) {
    int col = f % 112;
    int hr = f / 112;
    int row = hr & 127;
    int h = hr >> 7;
    float v = 0.f;
    if (row < NTOK && col < NTOK)
      v = bias_table[rel_index[row * NTOK + col] * 3 + h];
    bias_full[f] = v;
  }
}

// One block per window. 4 waves; wave w owns query rows [32w, 32w+32).
// All transposes are done with swapped-operand MFMAs + register quad-rechunk
// permutes (ds_bpermute) — k_lds/vT are read-only after the single barrier.
__global__ __launch_bounds__(256, 3) void wattn3d(
    const float* __restrict__ x, const float* __restrict__ qkv_b,
    const float* __restrict__ proj_b, const uint16_t* __restrict__ qkv_wp,
    const uint16_t* __restrict__ proj_wp, const float* __restrict__ bias_full,
    float* __restrict__ out) {
  // LDS: k_lds 20384 B | vT 23040 B | 128 B zeroed tail pad = 43552 B
  __shared__ __align__(16) char smem[43552];
  __bf16* k_lds = (__bf16*)smem;         // 98 rows x LDK
  __bf16* vT = (__bf16*)(smem + 20384);  // 96 rows x LDV

  const int tid = threadIdx.x;
  const int wave = tid >> 6;
  const int lane = tid & 63;
  const int quad = lane >> 4;
  const int l16 = lane & 15;
  const int b = blockIdx.x;
  const int rowbase = wave * 32;
  const float scale = 0.17677669529663687f;  // 32^-0.5

  // rechunk permute lane selectors (bytes) + parity select
  const int selA = (l16 | (((2 * quad) & 3) << 4)) << 2;
  const int selB = (l16 | (((2 * quad + 1) & 3) << 4)) << 2;
  const bool lowq = quad < 2;

  // zero vT pad tokens 112..119 and the 128 B tail pad (PV reads may spill)
  for (int i = tid; i < CDIM * 8; i += 256) {
    int d = i >> 3, tk = 112 + (i & 7);
    vT[d * LDV + tk] = (__bf16)0.0f;
  }
  if (tid < 32) ((uint32_t*)(smem + 43424))[tid] = 0u;

  const float* xb = x + (size_t)b * NTOK * CDIM;

  // ---------------- QKV GEMM ----------------
  bf16x8 a_x[2][3];
#pragma unroll
  for (int mt = 0; mt < 2; ++mt) {
    int row = rowbase + mt * 16 + l16;
#pragma unroll
    for (int kt = 0; kt < 3; ++kt) {
      if (row < NTOK) {
        a_x[mt][kt] = cvt8(xb + row * CDIM + kt * 32 + quad * 8);
      } else {
        bf16x8 z;
#pragma unroll
        for (int j = 0; j < 8; ++j) z[j] = (__bf16)0.0f;
        a_x[mt][kt] = z;
      }
    }
  }

  // q part: SWAPPED mfma(W, X^T) -> lane holds Q^T: 4 consecutive channels
  // c = nt*16+quad*4+i at q-row = rowbase+mt*16+l16. Pre-scaled, packed bf16.
  uint32_t qpk[2][6][2];
#pragma unroll
  for (int nt = 0; nt < 6; ++nt) {
    bf16x8 bw[3];
#pragma unroll
    for (int kt = 0; kt < 3; ++kt)
      bw[kt] = *(const bf16x8*)(qkv_wp + (((nt * 3 + kt) * 4 + quad) * 16 + l16) * 8);
    float4 qb4 = *(const float4*)&qkv_b[nt * 16 + quad * 4];
#pragma unroll
    for (int mt = 0; mt < 2; ++mt) {
      f32x4 acc = {0.f, 0.f, 0.f, 0.f};
#pragma unroll
      for (int kt = 0; kt < 3; ++kt)
        acc = __builtin_amdgcn_mfma_f32_16x16x32_bf16(bw[kt], a_x[mt][kt], acc, 0, 0, 0);
      qpk[mt][nt][0] = pk2((acc[0] + qb4.x) * scale, (acc[1] + qb4.y) * scale);
      qpk[mt][nt][1] = pk2((acc[2] + qb4.z) * scale, (acc[3] + qb4.w) * scale);
    }
  }

  // k/v parts: normal orientation, staged to LDS (as before)
#pragma unroll
  for (int nt = 6; nt < 18; ++nt) {
    bf16x8 bw[3];
#pragma unroll
    for (int kt = 0; kt < 3; ++kt)
      bw[kt] = *(const bf16x8*)(qkv_wp + (((nt * 3 + kt) * 4 + quad) * 16 + l16) * 8);
    float bn = qkv_b[nt * 16 + l16];
#pragma unroll
    for (int mt = 0; mt < 2; ++mt) {
      f32x4 acc = {0.f, 0.f, 0.f, 0.f};
#pragma unroll
      for (int kt = 0; kt < 3; ++kt)
        acc = __builtin_amdgcn_mfma_f32_16x16x32_bf16(a_x[mt][kt], bw[kt], acc, 0, 0, 0);
      if (nt < 12) {  // k, row-major; only real tokens stored
        int colb = (nt - 6) * 16 + l16;
#pragma unroll
        for (int i = 0; i < 4; ++i) {
          int row = rowbase + mt * 16 + quad * 4 + i;
          if (row < NTOK) k_lds[row * LDK + colb] = (__bf16)(acc[i] + bn);
        }
      } else {  // v, transposed: 4 consecutive tokens -> one 8B store
        int d = (nt - 12) * 16 + l16;
        int t0 = rowbase + mt * 16 + quad * 4;
        if (t0 < 112) {
          uint2 pk;
          pk.x = pk2(acc[0] + bn, acc[1] + bn);
          pk.y = pk2(acc[2] + bn, acc[3] + bn);
          *(uint2*)&vT[d * LDV + t0] = pk;
        }
      }
    }
  }
  __syncthreads();  // the ONLY block barrier; k_lds/vT read-only from here

  // ---------------- attention, head-by-head (wave-local, barrier-free) ------
  uint32_t opk[2][3][4];  // per-head O^T fragments (scaled, packed bf16)
  float rs[2];

#pragma unroll
  for (int h = 0; h < 3; ++h) {
    // Q B-fragment from channel-major qpk via quad-rechunk (no LDS)
    bf16x8 qf[2];
#pragma unroll
    for (int mt = 0; mt < 2; ++mt)
      qf[mt] = rechunk(qpk[mt][2 * h][0], qpk[mt][2 * h][1],
                       qpk[mt][2 * h + 1][0], qpk[mt][2 * h + 1][1],
                       selA, selB, lowq);

    // scores: S^T = mfma(K, Q): lane holds S[q=l16-row][tok=nt*16+quad*4+i]
    f32x4 sacc[2][7];
#pragma unroll
    for (int nt = 0; nt < 7; ++nt) {
      bf16x8 ak = *(bf16x8*)&k_lds[(nt * 16 + l16) * LDK + h * 32 + quad * 8];
#pragma unroll
      for (int mt = 0; mt < 2; ++mt) {
        f32x4 z = {0.f, 0.f, 0.f, 0.f};
        sacc[mt][nt] = __builtin_amdgcn_mfma_f32_16x16x32_bf16(ak, qf[mt], z, 0, 0, 0);
      }
    }

    // softmax: row q = l16 lives in the 4 quads of this l16 -> 2 shuffles/red.
#pragma unroll
    for (int mt = 0; mt < 2; ++mt) {
      const int qrow = rowbase + mt * 16 + l16;
      const float* brow = bias_full + ((size_t)h * 128 + qrow) * 112 + quad * 4;
      float mx = -1e30f;
#pragma unroll
      for (int nt = 0; nt < 7; ++nt) {
        float4 b4 = *(const float4*)(brow + nt * 16);
        float bv[4] = {b4.x, b4.y, b4.z, b4.w};
#pragma unroll
        for (int i = 0; i < 4; ++i) {
          float s = sacc[mt][nt][i] + bv[i];
          if (nt == 6 && !(quad == 0 && i < 2)) s = -1e30f;  // toks >= 98
          sacc[mt][nt][i] = s;
          mx = fmaxf(mx, s);
        }
      }
      mx = fmaxf(mx, __shfl_xor(mx, 16));
      mx = fmaxf(mx, __shfl_xor(mx, 32));
      float sum = 0.f;
#pragma unroll
      for (int nt = 0; nt < 7; ++nt)
#pragma unroll
        for (int i = 0; i < 4; ++i) {
          float p = __expf(sacc[mt][nt][i] - mx);
          sacc[mt][nt][i] = p;
          sum += p;
        }
      sum += __shfl_xor(sum, 16);
      sum += __shfl_xor(sum, 32);
      rs[mt] = 1.f / sum;
    }

    // PV: O^T = mfma(V^T, P^T); P^T B-frag via quad-rechunk of S^T regs
    f32x4 oacc[2][2];
#pragma unroll
    for (int mt = 0; mt < 2; ++mt)
#pragma unroll
      for (int nh = 0; nh < 2; ++nh) {
        f32x4 z = {0.f, 0.f, 0.f, 0.f};
        oacc[mt][nh] = z;
      }
#pragma unroll
    for (int kt2 = 0; kt2 < 4; ++kt2) {
      bf16x8 av[2];
#pragma unroll
      for (int nh = 0; nh < 2; ++nh)
        av[nh] = *(bf16x8*)&vT[(h * 32 + nh * 16 + l16) * LDV + kt2 * 32 + quad * 8];
#pragma unroll
      for (int mt = 0; mt < 2; ++mt) {
        uint32_t e0 = pk2(sacc[mt][2 * kt2][0], sacc[mt][2 * kt2][1]);
        uint32_t e1 = pk2(sacc[mt][2 * kt2][2], sacc[mt][2 * kt2][3]);
        uint32_t o0 = 0u, o1 = 0u;
        if (kt2 < 3) {  // kt2==3: toks 112..127 are exactly zero
          o0 = pk2(sacc[mt][2 * kt2 + 1][0], sacc[mt][2 * kt2 + 1][1]);
          o1 = pk2(sacc[mt][2 * kt2 + 1][2], sacc[mt][2 * kt2 + 1][3]);
        }
        bf16x8 pf = rechunk(e0, e1, o0, o1, selA, selB, lowq);
#pragma unroll
        for (int nh = 0; nh < 2; ++nh)
          oacc[mt][nh] = __builtin_amdgcn_mfma_f32_16x16x32_bf16(av[nh], pf, oacc[mt][nh], 0, 0, 0);
      }
    }

    // normalize + pack O^T for the proj B-fragment (channel-major, like qpk)
#pragma unroll
    for (int mt = 0; mt < 2; ++mt) {
      float r = rs[mt];
      opk[mt][h][0] = pk2(oacc[mt][0][0] * r, oacc[mt][0][1] * r);
      opk[mt][h][1] = pk2(oacc[mt][0][2] * r, oacc[mt][0][3] * r);
      opk[mt][h][2] = pk2(oacc[mt][1][0] * r, oacc[mt][1][1] * r);
      opk[mt][h][3] = pk2(oacc[mt][1][2] * r, oacc[mt][1][3] * r);
    }
  }

  // ---------------- proj: Y^T = mfma(Wp, O^T), fully in registers ----------
  float* outb = out + (size_t)b * NTOK * CDIM;
#pragma unroll
  for (int mt = 0; mt < 2; ++mt) {
    bf16x8 of[3];
#pragma unroll
    for (int kt = 0; kt < 3; ++kt)
      of[kt] = rechunk(opk[mt][kt][0], opk[mt][kt][1], opk[mt][kt][2],
                       opk[mt][kt][3], selA, selB, lowq);
    const int qrow = rowbase + mt * 16 + l16;
#pragma unroll
    for (int nt = 0; nt < 6; ++nt) {
      f32x4 acc = {0.f, 0.f, 0.f, 0.f};
#pragma unroll
      for (int kt = 0; kt < 3; ++kt) {
        bf16x8 aw = *(const bf16x8*)(proj_wp + (((nt * 3 + kt) * 4 + quad) * 16 + l16) * 8);
        acc = __builtin_amdgcn_mfma_f32_16x16x32_bf16(aw, of[kt], acc, 0, 0, 0);
      }
      if (qrow < NTOK) {
        float4 pb4 = *(const float4*)&proj_b[nt * 16 + quad * 4];
        float4 o4;
        o4.x = acc[0] + pb4.x;
        o4.y = acc[1] + pb4.y;
        o4.z = acc[2] + pb4.z;
        o4.w = acc[3] + pb4.w;
        *(float4*)&outb[(size_t)qrow * CDIM + nt * 16 + quad * 4] = o4;
      }
    }
  }
}

extern "C" void kernel_launch(void* const* d_in, const int* in_sizes, int n_in,
                              void* d_out, int out_size, void* d_ws, size_t ws_size,
                              hipStream_t stream) {
  (void)n_in; (void)out_size; (void)ws_size;
  const float* x = (const float*)d_in[0];
  const float* qkv_w = (const float*)d_in[1];
  const float* qkv_b = (const float*)d_in[2];
  const float* proj_w = (const float*)d_in[3];
  const float* proj_b = (const float*)d_in[4];
  const float* bias_table = (const float*)d_in[5];
  const int* rel_index = (const int*)d_in[6];
  float* out = (float*)d_out;

  uint16_t* qkv_wp = (uint16_t*)d_ws;                    // 55296 B
  uint16_t* proj_wp = (uint16_t*)((char*)d_ws + 55296);  // 18432 B
  float* bias_full = (float*)((char*)d_ws + 73728);      // 172032 B

  precompute<<<dim3(64), dim3(256), 0, stream>>>(qkv_w, proj_w, bias_table,
                                                 rel_index, qkv_wp, proj_wp,
                                                 bias_full);
  int Bwin = in_sizes[0] / (NTOK * CDIM);
  wattn3d<<<dim3(Bwin), dim3(256), 0, stream>>>(x, qkv_b, proj_b, qkv_wp,
                                                proj_wp, bias_full, out);
}